// Round 3
// baseline (1322.715 us; speedup 1.0000x reference)
//
#include <hip/hip_runtime.h>
#include <hip/hip_bf16.h>

// Problem constants
#define TOTAL_NODES 32768   // B*N = 64*512
#define NNODE 512
#define ETOT 524288         // B*E = 64*8192

// ---------------------------------------------------------------------------
// degree: deg[row[e]] += 1
__global__ void deg_kernel(const int* __restrict__ ei, float* __restrict__ deg) {
    int e = blockIdx.x * blockDim.x + threadIdx.x;
    if (e < ETOT) atomicAdd(&deg[ei[e]], 1.0f);
}

// deg = count + 1 ; dinv = rsqrt(deg)
__global__ void dinv_kernel(float* __restrict__ deg, float* __restrict__ dinv) {
    int n = blockIdx.x * blockDim.x + threadIdx.x;
    if (n < TOTAL_NODES) {
        float d = deg[n] + 1.0f;
        deg[n] = d;
        dinv[n] = rsqrtf(d);
    }
}

// ---------------------------------------------------------------------------
// Row-tiled GEMM: out[r, c] = in[r, :128] @ W[128, OUTC] (+ bias), fp32.
// 8 rows per block, OUTC threads. fp32 accumulate.
template <int OUTC>
__global__ __launch_bounds__(256) void gemm_kernel(const float* __restrict__ in,
                                                   const float* __restrict__ W,
                                                   const float* __restrict__ bias,
                                                   float* __restrict__ outp) {
    __shared__ __align__(16) float a_lds[8 * 128];
    const int rb = blockIdx.x * 8;
    const int t = threadIdx.x;
    for (int idx = t; idx < 8 * 128; idx += OUTC)
        a_lds[idx] = in[(size_t)(rb + (idx >> 7)) * 128 + (idx & 127)];
    __syncthreads();

    float acc[8];
    float bv = bias ? bias[t] : 0.0f;
#pragma unroll
    for (int r = 0; r < 8; r++) acc[r] = bv;

    const float4* a4 = (const float4*)a_lds;
    for (int k4 = 0; k4 < 32; k4++) {
        float w0 = W[(k4 * 4 + 0) * OUTC + t];
        float w1 = W[(k4 * 4 + 1) * OUTC + t];
        float w2 = W[(k4 * 4 + 2) * OUTC + t];
        float w3 = W[(k4 * 4 + 3) * OUTC + t];
#pragma unroll
        for (int r = 0; r < 8; r++) {
            float4 a = a4[r * 32 + k4];
            acc[r] = fmaf(a.x, w0, fmaf(a.y, w1, fmaf(a.z, w2, fmaf(a.w, w3, acc[r]))));
        }
    }
#pragma unroll
    for (int r = 0; r < 8; r++) outp[(size_t)(rb + r) * OUTC + t] = acc[r];
}

// ---------------------------------------------------------------------------
// message pass: agg[col] += dinv[row]*dinv[col] * relu(h0[row] + ee[e])
// 2 edges per block, 128 threads per edge (one per feature dim).
__global__ void msg_kernel(const int* __restrict__ ei, const float* __restrict__ ee,
                           const float* __restrict__ h0, const float* __restrict__ dinv,
                           float* __restrict__ agg) {
    int e = blockIdx.x * 2 + (threadIdx.x >> 7);
    int d = threadIdx.x & 127;
    int r = ei[e];
    int c = ei[ETOT + e];
    float nrm = dinv[r] * dinv[c];
    float v = h0[(size_t)r * 128 + d] + ee[(size_t)e * 128 + d];
    atomicAdd(&agg[(size_t)c * 128 + d], fmaxf(v, 0.0f) * nrm);
}

// h = agg + relu(h0 + root_emb) / deg   (in place: agg becomes h)
__global__ void combine_kernel(const float* __restrict__ h0, float* __restrict__ agg,
                               const float* __restrict__ deg, const float* __restrict__ root) {
    int i = blockIdx.x * blockDim.x + threadIdx.x;
    int n = i >> 7, d = i & 127;
    float v = h0[i] + root[d];
    agg[i] += fmaxf(v, 0.0f) / deg[n];
}

// ---------------------------------------------------------------------------
// Attention for one (b, head, 64-row split). K kept in registers (2 rows per
// thread, fp32). q staged in LDS. Softmax via wave shuffles + LDS cross-wave.
// P through LDS; V streamed from global. ao may alias qbuf: each block writes
// exactly the (row, col) region only it reads.
__global__ __launch_bounds__(256) void attn_kernel(const float* __restrict__ qbuf,
                                                   const float* __restrict__ kvbuf,
                                                   float* __restrict__ ao) {
    __shared__ __align__(16) float q_lds[8 * 32];
    __shared__ __align__(16) float p_lds[8 * NNODE];
    __shared__ float wred[32];
    const int t = threadIdx.x;
    const int bh = blockIdx.y;          // 0..255
    const int b = bh >> 2, head = bh & 3;
    const int hoff = head * 32;
    const size_t nbase = (size_t)b * NNODE;
    const int split = blockIdx.x;       // 0..7 -> 64 rows each

    // preload K rows t and t+256 (32 floats each)
    float kr0[32], kr1[32];
    {
        const float4* kp0 = (const float4*)(kvbuf + (nbase + t) * 256 + hoff);
        const float4* kp1 = (const float4*)(kvbuf + (nbase + t + 256) * 256 + hoff);
#pragma unroll
        for (int x = 0; x < 8; x++) {
            float4 a = kp0[x];
            kr0[4 * x] = a.x; kr0[4 * x + 1] = a.y; kr0[4 * x + 2] = a.z; kr0[4 * x + 3] = a.w;
            float4 c = kp1[x];
            kr1[4 * x] = c.x; kr1[4 * x + 1] = c.y; kr1[4 * x + 2] = c.z; kr1[4 * x + 3] = c.w;
        }
    }
    const int lane = t & 63, wid = t >> 6;
    const int dl = t & 31, cg = t >> 5;

    for (int tile = 0; tile < 8; tile++) {
        const int i0 = split * 64 + tile * 8;
        {   // stage q (scale folded in)
            int r = t >> 5, d = t & 31;
            q_lds[t] = qbuf[(nbase + i0 + r) * 128 + hoff + d] * 0.17677669529663687f;
        }
        __syncthreads();

        // QK^T: s[2r+jj] = q_row_r . k_row_(t + 256*jj)
        float s[16];
        const float4* q4 = (const float4*)q_lds;
#pragma unroll
        for (int r = 0; r < 8; r++) {
            float a0 = 0.f, a1 = 0.f;
#pragma unroll
            for (int x = 0; x < 8; x++) {
                float4 qv = q4[r * 8 + x];
                a0 += qv.x * kr0[4 * x] + qv.y * kr0[4 * x + 1] + qv.z * kr0[4 * x + 2] + qv.w * kr0[4 * x + 3];
                a1 += qv.x * kr1[4 * x] + qv.y * kr1[4 * x + 1] + qv.z * kr1[4 * x + 2] + qv.w * kr1[4 * x + 3];
            }
            s[2 * r] = a0;
            s[2 * r + 1] = a1;
        }

        // softmax over j (512 values per row, spread across all 256 threads)
        float mxr[8];
#pragma unroll
        for (int r = 0; r < 8; r++) {
            float m2 = fmaxf(s[2 * r], s[2 * r + 1]);
#pragma unroll
            for (int off = 32; off >= 1; off >>= 1) m2 = fmaxf(m2, __shfl_xor(m2, off));
            if (lane == 0) wred[wid * 8 + r] = m2;
        }
        __syncthreads();
#pragma unroll
        for (int r = 0; r < 8; r++)
            mxr[r] = fmaxf(fmaxf(wred[r], wred[8 + r]), fmaxf(wred[16 + r], wred[24 + r]));
        __syncthreads();
#pragma unroll
        for (int r = 0; r < 8; r++) {
            float p0 = __expf(s[2 * r] - mxr[r]);
            float p1 = __expf(s[2 * r + 1] - mxr[r]);
            s[2 * r] = p0;
            s[2 * r + 1] = p1;
            float l2 = p0 + p1;
#pragma unroll
            for (int off = 32; off >= 1; off >>= 1) l2 += __shfl_xor(l2, off);
            if (lane == 0) wred[wid * 8 + r] = l2;
        }
        __syncthreads();
#pragma unroll
        for (int r = 0; r < 8; r++) {
            float inv = 1.0f / (wred[r] + wred[8 + r] + wred[16 + r] + wred[24 + r]);
            p_lds[r * NNODE + t] = s[2 * r] * inv;
            p_lds[r * NNODE + t + 256] = s[2 * r + 1] * inv;
        }
        __syncthreads();

        // PV: thread (dl, cg) handles j in [cg*64, cg*64+64), all 8 rows
        float acc[8] = {0, 0, 0, 0, 0, 0, 0, 0};
        const float4* p4 = (const float4*)p_lds;
        for (int j4 = 0; j4 < 16; j4++) {
            const int j = cg * 64 + j4 * 4;
            const float* vb = kvbuf + (nbase + j) * 256 + 128 + hoff + dl;
            float v0 = vb[0], v1 = vb[256], v2 = vb[512], v3 = vb[768];
#pragma unroll
            for (int r = 0; r < 8; r++) {
                float4 p = p4[r * 128 + (j >> 2)];
                acc[r] += p.x * v0 + p.y * v1 + p.z * v2 + p.w * v3;
            }
        }
        __syncthreads();
        // reduce 8 cg-partials per (r, dl) through LDS scratch (reuse p_lds)
#pragma unroll
        for (int r = 0; r < 8; r++) p_lds[(r * 32 + dl) * 8 + cg] = acc[r];
        __syncthreads();
        {
            int rr = t >> 5, dd = t & 31;
            const float* rp = p_lds + (rr * 32 + dd) * 8;
            float v = rp[0] + rp[1] + rp[2] + rp[3] + rp[4] + rp[5] + rp[6] + rp[7];
            ao[(nbase + i0 + rr) * 128 + hoff + dd] = v;
        }
        __syncthreads();
    }
}

// ---------------------------------------------------------------------------
extern "C" void kernel_launch(void* const* d_in, const int* in_sizes, int n_in,
                              void* d_out, int out_size, void* d_ws, size_t ws_size,
                              hipStream_t stream) {
    const float* x    = (const float*)d_in[0];
    const int*   ei   = (const int*)d_in[1];
    const float* ee   = (const float*)d_in[2];
    // d_in[3] = batch (unused; uniform graphs)
    const float* Wg   = (const float*)d_in[4];
    const float* bg   = (const float*)d_in[5];
    const float* root = (const float*)d_in[6];
    const float* Wq   = (const float*)d_in[7];
    const float* Wkv  = (const float*)d_in[8];
    const float* Wo   = (const float*)d_in[9];
    const float* bo   = (const float*)d_in[10];

    // Workspace: 67.4 MB fp32
    float* ws   = (float*)d_ws;
    float* deg  = ws;                    // 32768
    float* dinv = ws + 32768;            // 32768
    float* buf1 = ws + 65536;            // 4.19M floats: h0 -> q -> attn_out
    float* agg  = buf1 + 4194304;        // 4.19M floats: agg -> h (in place)
    float* kv   = agg + 4194304;         // 8.39M floats
    // total: 16,842,752 floats = 67.4 MB

    hipMemsetAsync(deg, 0, 131072, stream);
    hipMemsetAsync(agg, 0, 16777216, stream);

    deg_kernel<<<2048, 256, 0, stream>>>(ei, deg);
    dinv_kernel<<<128, 256, 0, stream>>>(deg, dinv);

    // h0 = x @ W_gcn + b_gcn
    gemm_kernel<128><<<4096, 128, 0, stream>>>(x, Wg, bg, buf1);
    // agg (fp32 atomics)
    msg_kernel<<<262144, 256, 0, stream>>>(ei, ee, buf1, dinv, agg);
    // h = agg + relu(h0 + root)/deg  (in place in agg)
    combine_kernel<<<16384, 256, 0, stream>>>(buf1, agg, deg, root);

    // q = h @ Wq ; kv = h @ Wkv
    gemm_kernel<128><<<4096, 128, 0, stream>>>(agg, Wq, nullptr, buf1);
    gemm_kernel<256><<<4096, 256, 0, stream>>>(agg, Wkv, nullptr, kv);

    // attention -> buf1 (aliases q; per-block disjoint read/write regions)
    attn_kernel<<<dim3(8, 256), 256, 0, stream>>>(buf1, kv, buf1);

    // out = attn_out @ Wout + b_out
    gemm_kernel<128><<<4096, 128, 0, stream>>>(buf1, Wo, bo, (float*)d_out);
}

// Round 4
// 769.198 us; speedup vs baseline: 1.7196x; 1.7196x over previous
//
#include <hip/hip_runtime.h>
#include <hip/hip_bf16.h>

// Problem constants
#define TOTAL_NODES 32768   // B*N = 64*512
#define NNODE 512
#define ETOT 524288         // B*E = 64*8192

typedef unsigned short u16;
typedef __attribute__((ext_vector_type(8))) short bf16x8;
typedef __attribute__((ext_vector_type(4))) float f32x4;

union U8 { bf16x8 v; u16 s[8]; uint4 q; };

__device__ __forceinline__ float bf2f(u16 u) {
    union { unsigned int i; float f; } x; x.i = ((unsigned int)u) << 16; return x.f;
}
__device__ __forceinline__ u16 f2bf(float f) {
    union { __hip_bfloat16 h; u16 u; } c; c.h = __float2bfloat16(f); return c.u;
}
__device__ __forceinline__ f32x4 mfma16(bf16x8 a, bf16x8 b, f32x4 c) {
    return __builtin_amdgcn_mfma_f32_16x16x32_bf16(a, b, c, 0, 0, 0);
}

// ---------------------------------------------------------------------------
__global__ void deg_kernel(const int* __restrict__ ei, float* __restrict__ deg) {
    int e = blockIdx.x * blockDim.x + threadIdx.x;
    if (e < ETOT) atomicAdd(&deg[ei[e]], 1.0f);
}

__global__ void dinv_kernel(float* __restrict__ deg, float* __restrict__ dinv) {
    int n = blockIdx.x * blockDim.x + threadIdx.x;
    if (n < TOTAL_NODES) {
        float d = deg[n] + 1.0f;
        deg[n] = d;
        dinv[n] = rsqrtf(d);
    }
}

// ---------------------------------------------------------------------------
// Row-tiled GEMM: out[r, c] = in[r, :128] @ W[128, OUTC] (+ bias), fp32.
template <int OUTC>
__global__ __launch_bounds__(256) void gemm_kernel(const float* __restrict__ in,
                                                   const float* __restrict__ W,
                                                   const float* __restrict__ bias,
                                                   float* __restrict__ outp) {
    __shared__ __align__(16) float a_lds[8 * 128];
    const int rb = blockIdx.x * 8;
    const int t = threadIdx.x;
    for (int idx = t; idx < 8 * 128; idx += OUTC)
        a_lds[idx] = in[(size_t)(rb + (idx >> 7)) * 128 + (idx & 127)];
    __syncthreads();

    float acc[8];
    float bv = bias ? bias[t] : 0.0f;
#pragma unroll
    for (int r = 0; r < 8; r++) acc[r] = bv;

    const float4* a4 = (const float4*)a_lds;
    for (int k4 = 0; k4 < 32; k4++) {
        float w0 = W[(k4 * 4 + 0) * OUTC + t];
        float w1 = W[(k4 * 4 + 1) * OUTC + t];
        float w2 = W[(k4 * 4 + 2) * OUTC + t];
        float w3 = W[(k4 * 4 + 3) * OUTC + t];
#pragma unroll
        for (int r = 0; r < 8; r++) {
            float4 a = a4[r * 32 + k4];
            acc[r] = fmaf(a.x, w0, fmaf(a.y, w1, fmaf(a.z, w2, fmaf(a.w, w3, acc[r]))));
        }
    }
#pragma unroll
    for (int r = 0; r < 8; r++) outp[(size_t)(rb + r) * OUTC + t] = acc[r];
}

// ---------------------------------------------------------------------------
__global__ void msg_kernel(const int* __restrict__ ei, const float* __restrict__ ee,
                           const float* __restrict__ h0, const float* __restrict__ dinv,
                           float* __restrict__ agg) {
    int e = blockIdx.x * 2 + (threadIdx.x >> 7);
    int d = threadIdx.x & 127;
    int r = ei[e];
    int c = ei[ETOT + e];
    float nrm = dinv[r] * dinv[c];
    float v = h0[(size_t)r * 128 + d] + ee[(size_t)e * 128 + d];
    atomicAdd(&agg[(size_t)c * 128 + d], fmaxf(v, 0.0f) * nrm);
}

__global__ void combine_kernel(const float* __restrict__ h0, float* __restrict__ agg,
                               const float* __restrict__ deg, const float* __restrict__ root) {
    int i = blockIdx.x * blockDim.x + threadIdx.x;
    int n = i >> 7, d = i & 127;
    float v = h0[i] + root[d];
    agg[i] += fmaxf(v, 0.0f) / deg[n];
}

// ---------------------------------------------------------------------------
// prep: kv fp32 [node][256] -> khi/klo bf16 [bh][node][32], vT bf16 [bh][32][512]
// one block per (b,h)
__global__ __launch_bounds__(256) void prep_kernel(const float* __restrict__ kv,
                                                   u16* __restrict__ khi,
                                                   u16* __restrict__ klo,
                                                   u16* __restrict__ vT) {
    __shared__ float vtile[64 * 33];
    const int t = threadIdx.x;
    const int bh = blockIdx.x, b = bh >> 2, h = bh & 3;
    const int hoff = h * 32;
    // K: hi/lo split
    for (int idx = t; idx < 512 * 32; idx += 256) {
        int n = idx >> 5, d = idx & 31;
        float f = kv[(size_t)(b * 512 + n) * 256 + hoff + d];
        u16 hi = f2bf(f);
        khi[(size_t)bh * 16384 + idx] = hi;
        klo[(size_t)bh * 16384 + idx] = f2bf(f - bf2f(hi));
    }
    // V: transpose via LDS (row pad 33 breaks bank conflicts)
    for (int c = 0; c < 8; c++) {
        __syncthreads();
        for (int i = t; i < 64 * 32; i += 256) {
            int n0 = i >> 5, d = i & 31;
            vtile[n0 * 33 + d] = kv[(size_t)(b * 512 + c * 64 + n0) * 256 + 128 + hoff + d];
        }
        __syncthreads();
        for (int i = t; i < 32 * 64; i += 256) {
            int d = i >> 6, n0 = i & 63;
            vT[(size_t)(bh * 32 + d) * 512 + c * 64 + n0] = f2bf(vtile[n0 * 33 + d]);
        }
    }
}

// ---------------------------------------------------------------------------
// MFMA attention. Grid (4 q-splits, 256 bh), 256 threads = 4 waves.
// Each wave: 2 q-tiles of 16 rows (shared B loads). Two-pass softmax:
// pass1 = approximate row-max (1 mfma/tile), pass2 = exact S (3-term hi/lo
// split), P -> per-wave LDS transit (C-layout -> A-layout), PV in bf16.
// ao may alias qbuf: each block writes exactly the region only it reads.
__global__ __launch_bounds__(256) void attn_mfma_kernel(const float* __restrict__ qbuf,
                                                        const u16* __restrict__ khi,
                                                        const u16* __restrict__ klo,
                                                        const u16* __restrict__ vT,
                                                        float* __restrict__ ao) {
    __shared__ u16 transit[8][16 * 36];   // [wave*2+p][row*36 + col], stride 36 u16
    const int t = threadIdx.x;
    const int w = t >> 6, L = t & 63;
    const int n16 = L & 15, quad = L >> 4;
    const int bh = blockIdx.y, b = bh >> 2, h = bh & 3;
    const int qbase = blockIdx.x * 128 + w * 32;

    // Load Q (scale folded), split hi/lo, A-layout: A[m=n16][k=quad*8+j]
    bf16x8 qhi[2], qlo[2];
#pragma unroll
    for (int p = 0; p < 2; p++) {
        const float* qp = qbuf + (size_t)(b * 512 + qbase + p * 16 + n16) * 128 + h * 32 + quad * 8;
        U8 uh, ul;
#pragma unroll
        for (int j = 0; j < 8; j++) {
            float f = qp[j] * 0.17677669529663687f;
            u16 hi = f2bf(f);
            uh.s[j] = hi;
            ul.s[j] = f2bf(f - bf2f(hi));
        }
        qhi[p] = uh.v; qlo[p] = ul.v;
    }

    const f32x4 zero = {0.f, 0.f, 0.f, 0.f};

    // ---- pass 1: approximate per-row max (hi-only) ----
    float m[2][4];
#pragma unroll
    for (int p = 0; p < 2; p++)
#pragma unroll
        for (int r = 0; r < 4; r++) m[p][r] = -1e30f;

    for (int j0 = 0; j0 < 512; j0 += 16) {
        U8 ub; ub.q = *(const uint4*)(khi + (size_t)(bh * 512 + j0 + n16) * 32 + quad * 8);
#pragma unroll
        for (int p = 0; p < 2; p++) {
            f32x4 s = mfma16(qhi[p], ub.v, zero);
#pragma unroll
            for (int r = 0; r < 4; r++) m[p][r] = fmaxf(m[p][r], s[r]);
        }
    }
#pragma unroll
    for (int p = 0; p < 2; p++)
#pragma unroll
        for (int r = 0; r < 4; r++) {
            float mv = m[p][r];
#pragma unroll
            for (int mask = 1; mask < 16; mask <<= 1) mv = fmaxf(mv, __shfl_xor(mv, mask));
            m[p][r] = mv;
        }

    // ---- pass 2: exact S (3-term), P, PV ----
    float l[2][4] = {{0.f, 0.f, 0.f, 0.f}, {0.f, 0.f, 0.f, 0.f}};
    f32x4 O[2][2];
#pragma unroll
    for (int p = 0; p < 2; p++)
#pragma unroll
        for (int dt = 0; dt < 2; dt++) O[p][dt] = zero;

    u16* tr[2] = { transit[w * 2 + 0], transit[w * 2 + 1] };

    for (int jb = 0; jb < 512; jb += 32) {
#pragma unroll
        for (int jt = 0; jt < 2; jt++) {
            const int j0 = jb + jt * 16;
            const size_t kidx = (size_t)(bh * 512 + j0 + n16) * 32 + quad * 8;
            U8 uh; uh.q = *(const uint4*)(khi + kidx);
            U8 ul; ul.q = *(const uint4*)(klo + kidx);
#pragma unroll
            for (int p = 0; p < 2; p++) {
                f32x4 s = mfma16(qhi[p], uh.v, zero);
                s = mfma16(qhi[p], ul.v, s);
                s = mfma16(qlo[p], uh.v, s);
                // C layout: row = quad*4+r, col = n16
#pragma unroll
                for (int r = 0; r < 4; r++) {
                    float pr = __expf(s[r] - m[p][r]);
                    u16 pb = f2bf(pr);
                    l[p][r] += bf2f(pb);     // sum the ROUNDED value -> matches PV
                    tr[p][(quad * 4 + r) * 36 + jt * 16 + n16] = pb;
                }
            }
        }
        // A-layout read: A[m=n16][k=quad*8+j]  (compiler inserts lgkmcnt waits)
        bf16x8 A[2];
#pragma unroll
        for (int p = 0; p < 2; p++) {
            const u16* trp = tr[p];
            const int off = n16 * 36 + quad * 8;
            uint2 lo = *(const uint2*)(trp + off);
            uint2 hi2 = *(const uint2*)(trp + off + 4);
            U8 ua; ua.q = make_uint4(lo.x, lo.y, hi2.x, hi2.y);
            A[p] = ua.v;
        }
#pragma unroll
        for (int dt = 0; dt < 2; dt++) {
            U8 uv; uv.q = *(const uint4*)(vT + (size_t)(bh * 32 + dt * 16 + n16) * 512 + jb + quad * 8);
#pragma unroll
            for (int p = 0; p < 2; p++) O[p][dt] = mfma16(A[p], uv.v, O[p][dt]);
        }
    }

    // ---- normalize + store (C layout: row = quad*4+r, col = n16) ----
#pragma unroll
    for (int p = 0; p < 2; p++)
#pragma unroll
        for (int r = 0; r < 4; r++) {
            float lv = l[p][r];
#pragma unroll
            for (int mask = 1; mask < 16; mask <<= 1) lv += __shfl_xor(lv, mask);
            float inv = 1.0f / lv;
#pragma unroll
            for (int dt = 0; dt < 2; dt++)
                ao[(size_t)(b * 512 + qbase + p * 16 + quad * 4 + r) * 128 + h * 32 + dt * 16 + n16]
                    = O[p][dt][r] * inv;
        }
}

// ---------------------------------------------------------------------------
extern "C" void kernel_launch(void* const* d_in, const int* in_sizes, int n_in,
                              void* d_out, int out_size, void* d_ws, size_t ws_size,
                              hipStream_t stream) {
    const float* x    = (const float*)d_in[0];
    const int*   ei   = (const int*)d_in[1];
    const float* ee   = (const float*)d_in[2];
    // d_in[3] = batch (unused; uniform graphs)
    const float* Wg   = (const float*)d_in[4];
    const float* bg   = (const float*)d_in[5];
    const float* root = (const float*)d_in[6];
    const float* Wq   = (const float*)d_in[7];
    const float* Wkv  = (const float*)d_in[8];
    const float* Wo   = (const float*)d_in[9];
    const float* bo   = (const float*)d_in[10];

    // Workspace: 67.4 MB fp32 (known-good size from round 3)
    float* ws   = (float*)d_ws;
    float* deg  = ws;                    // 32768
    float* dinv = ws + 32768;            // 32768
    float* buf1 = ws + 65536;            // 4.19M floats: h0 -> q -> attn_out
    float* agg  = buf1 + 4194304;        // 4.19M floats: agg -> h -> khi/klo
    float* kv   = agg + 4194304;         // 8.39M floats
    u16*   khi  = (u16*)agg;             // 8 MB (after h is dead)
    u16*   klo  = khi + 4194304;         // 8 MB
    u16*   vT   = (u16*)d_out;           // 8 MB scratch in d_out (fully overwritten later)

    hipMemsetAsync(deg, 0, 131072, stream);
    hipMemsetAsync(agg, 0, 16777216, stream);

    deg_kernel<<<2048, 256, 0, stream>>>(ei, deg);
    dinv_kernel<<<128, 256, 0, stream>>>(deg, dinv);

    // h0 = x @ W_gcn + b_gcn
    gemm_kernel<128><<<4096, 128, 0, stream>>>(x, Wg, bg, buf1);
    // agg (fp32 atomics)
    msg_kernel<<<262144, 256, 0, stream>>>(ei, ee, buf1, dinv, agg);
    // h = agg + relu(h0 + root)/deg  (in place in agg)
    combine_kernel<<<16384, 256, 0, stream>>>(buf1, agg, deg, root);

    // q = h @ Wq ; kv = h @ Wkv
    gemm_kernel<128><<<4096, 128, 0, stream>>>(agg, Wq, nullptr, buf1);
    gemm_kernel<256><<<4096, 256, 0, stream>>>(agg, Wkv, nullptr, kv);

    // prep: kv -> khi/klo (over dead h in agg) + vT (in d_out)
    prep_kernel<<<256, 256, 0, stream>>>(kv, khi, klo, vT);

    // MFMA attention -> buf1 (aliases q; per-block disjoint read/write regions)
    attn_mfma_kernel<<<dim3(4, 256), 256, 0, stream>>>(buf1, khi, klo, vT, buf1);

    // out = attn_out @ Wout + b_out
    gemm_kernel<128><<<4096, 128, 0, stream>>>(buf1, Wo, bo, (float*)d_out);
}

// Round 5
// 653.850 us; speedup vs baseline: 2.0230x; 1.1764x over previous
//
#include <hip/hip_runtime.h>
#include <hip/hip_bf16.h>

// Problem constants
#define TOTAL_NODES 32768   // B*N = 64*512
#define NNODE 512
#define ETOT 524288         // B*E = 64*8192

typedef unsigned short u16;
typedef __attribute__((ext_vector_type(8))) short bf16x8;
typedef __attribute__((ext_vector_type(4))) float f32x4;

union U8 { bf16x8 v; u16 s[8]; uint4 q; };

__device__ __forceinline__ float bf2f(u16 u) {
    union { unsigned int i; float f; } x; x.i = ((unsigned int)u) << 16; return x.f;
}
__device__ __forceinline__ u16 f2bf(float f) {
    union { __hip_bfloat16 h; u16 u; } c; c.h = __float2bfloat16(f); return c.u;
}
__device__ __forceinline__ f32x4 mfma16(bf16x8 a, bf16x8 b, f32x4 c) {
    return __builtin_amdgcn_mfma_f32_16x16x32_bf16(a, b, c, 0, 0, 0);
}

// ---------------------------------------------------------------------------
// histogram: cnt_row[row[e]]++, cnt_col[col[e]]++  (int atomics, L2-resident)
__global__ void hist_kernel(const int* __restrict__ ei, int* __restrict__ cnt_row,
                            int* __restrict__ cnt_col) {
    int e = blockIdx.x * blockDim.x + threadIdx.x;
    if (e < ETOT) {
        atomicAdd(&cnt_row[ei[e]], 1);
        atomicAdd(&cnt_col[ei[ETOT + e]], 1);
    }
}

// dinv = rsqrt(cnt_row + 1)
__global__ void dinv_kernel(const int* __restrict__ cnt_row, float* __restrict__ dinv) {
    int n = blockIdx.x * blockDim.x + threadIdx.x;
    if (n < TOTAL_NODES) dinv[n] = rsqrtf((float)cnt_row[n] + 1.0f);
}

// exclusive prefix scan over cnt_col[32768] -> offs[32769], cur[32768]
__global__ __launch_bounds__(1024) void scan_kernel(const int* __restrict__ cnt,
                                                    int* __restrict__ offs,
                                                    int* __restrict__ cur) {
    __shared__ int part[1024];
    const int t = threadIdx.x;
    const int base = t * 32;
    int local[32];
    int s = 0;
#pragma unroll
    for (int i = 0; i < 32; i++) { local[i] = s; s += cnt[base + i]; }
    part[t] = s;
    __syncthreads();
    for (int off = 1; off < 1024; off <<= 1) {
        int v = (t >= off) ? part[t - off] : 0;
        __syncthreads();
        part[t] += v;
        __syncthreads();
    }
    int prefix = (t == 0) ? 0 : part[t - 1];
#pragma unroll
    for (int i = 0; i < 32; i++) {
        int o = prefix + local[i];
        offs[base + i] = o;
        cur[base + i] = o;
    }
    if (t == 1023) offs[32768] = prefix + s;
}

// scatter edge ids into CSR-by-col order
__global__ void scatter_kernel(const int* __restrict__ ei, int* __restrict__ cur,
                               int2* __restrict__ pairs) {
    int e = blockIdx.x * blockDim.x + threadIdx.x;
    if (e < ETOT) {
        int r = ei[e], c = ei[ETOT + e];
        int pos = atomicAdd(&cur[c], 1);
        pairs[pos] = make_int2(r, e);
    }
}

// gather: h[c] = dinv[c] * sum_in(dinv[r]*relu(h0[r]+ee[e])) + relu(h0[c]+root)/deg[c]
// one 128-thread block per destination node; atomic-free, single write.
__global__ __launch_bounds__(128) void gather_kernel(const int2* __restrict__ pairs,
                                                     const int* __restrict__ offs,
                                                     const int* __restrict__ cnt_row,
                                                     const float* __restrict__ dinv,
                                                     const float* __restrict__ h0,
                                                     const float* __restrict__ ee,
                                                     const float* __restrict__ root,
                                                     float* __restrict__ h) {
    const int c = blockIdx.x;
    const int d = threadIdx.x;
    const int s = offs[c], e_end = offs[c + 1];
    float acc = 0.0f;
    int i = s;
    for (; i + 2 <= e_end; i += 2) {
        int2 p0 = pairs[i], p1 = pairs[i + 1];
        float d0 = dinv[p0.x], d1 = dinv[p1.x];
        float v0 = h0[(size_t)p0.x * 128 + d] + ee[(size_t)p0.y * 128 + d];
        float v1 = h0[(size_t)p1.x * 128 + d] + ee[(size_t)p1.y * 128 + d];
        acc += fmaxf(v0, 0.0f) * d0 + fmaxf(v1, 0.0f) * d1;
    }
    for (; i < e_end; i++) {
        int2 p0 = pairs[i];
        float v0 = h0[(size_t)p0.x * 128 + d] + ee[(size_t)p0.y * 128 + d];
        acc += fmaxf(v0, 0.0f) * dinv[p0.x];
    }
    float degc = (float)cnt_row[c] + 1.0f;
    float hv = h0[(size_t)c * 128 + d] + root[d];
    h[(size_t)c * 128 + d] = dinv[c] * acc + fmaxf(hv, 0.0f) / degc;
}

// ---------------------------------------------------------------------------
// Row-tiled GEMM: out[r, c] = in[r, :128] @ W[128, OUTC] (+ bias), fp32.
template <int OUTC>
__global__ __launch_bounds__(256) void gemm_kernel(const float* __restrict__ in,
                                                   const float* __restrict__ W,
                                                   const float* __restrict__ bias,
                                                   float* __restrict__ outp) {
    __shared__ __align__(16) float a_lds[8 * 128];
    const int rb = blockIdx.x * 8;
    const int t = threadIdx.x;
    for (int idx = t; idx < 8 * 128; idx += OUTC)
        a_lds[idx] = in[(size_t)(rb + (idx >> 7)) * 128 + (idx & 127)];
    __syncthreads();

    float acc[8];
    float bv = bias ? bias[t] : 0.0f;
#pragma unroll
    for (int r = 0; r < 8; r++) acc[r] = bv;

    const float4* a4 = (const float4*)a_lds;
    for (int k4 = 0; k4 < 32; k4++) {
        float w0 = W[(k4 * 4 + 0) * OUTC + t];
        float w1 = W[(k4 * 4 + 1) * OUTC + t];
        float w2 = W[(k4 * 4 + 2) * OUTC + t];
        float w3 = W[(k4 * 4 + 3) * OUTC + t];
#pragma unroll
        for (int r = 0; r < 8; r++) {
            float4 a = a4[r * 32 + k4];
            acc[r] = fmaf(a.x, w0, fmaf(a.y, w1, fmaf(a.z, w2, fmaf(a.w, w3, acc[r]))));
        }
    }
#pragma unroll
    for (int r = 0; r < 8; r++) outp[(size_t)(rb + r) * OUTC + t] = acc[r];
}

// ---------------------------------------------------------------------------
// prep: kv fp32 [node][256] -> khi/klo bf16 [bh][node][32], vT bf16 [bh][32][512]
__global__ __launch_bounds__(256) void prep_kernel(const float* __restrict__ kv,
                                                   u16* __restrict__ khi,
                                                   u16* __restrict__ klo,
                                                   u16* __restrict__ vT) {
    __shared__ float vtile[64 * 33];
    const int t = threadIdx.x;
    const int bh = blockIdx.x, b = bh >> 2, h = bh & 3;
    const int hoff = h * 32;
    for (int idx = t; idx < 512 * 32; idx += 256) {
        int n = idx >> 5, d = idx & 31;
        float f = kv[(size_t)(b * 512 + n) * 256 + hoff + d];
        u16 hi = f2bf(f);
        khi[(size_t)bh * 16384 + idx] = hi;
        klo[(size_t)bh * 16384 + idx] = f2bf(f - bf2f(hi));
    }
    for (int c = 0; c < 8; c++) {
        __syncthreads();
        for (int i = t; i < 64 * 32; i += 256) {
            int n0 = i >> 5, d = i & 31;
            vtile[n0 * 33 + d] = kv[(size_t)(b * 512 + c * 64 + n0) * 256 + 128 + hoff + d];
        }
        __syncthreads();
        for (int i = t; i < 32 * 64; i += 256) {
            int d = i >> 6, n0 = i & 63;
            vT[(size_t)(bh * 32 + d) * 512 + c * 64 + n0] = f2bf(vtile[n0 * 33 + d]);
        }
    }
}

// ---------------------------------------------------------------------------
// MFMA attention (unchanged from round 4).
__global__ __launch_bounds__(256) void attn_mfma_kernel(const float* __restrict__ qbuf,
                                                        const u16* __restrict__ khi,
                                                        const u16* __restrict__ klo,
                                                        const u16* __restrict__ vT,
                                                        float* __restrict__ ao) {
    __shared__ u16 transit[8][16 * 36];
    const int t = threadIdx.x;
    const int w = t >> 6, L = t & 63;
    const int n16 = L & 15, quad = L >> 4;
    const int bh = blockIdx.y, b = bh >> 2, h = bh & 3;
    const int qbase = blockIdx.x * 128 + w * 32;

    bf16x8 qhi[2], qlo[2];
#pragma unroll
    for (int p = 0; p < 2; p++) {
        const float* qp = qbuf + (size_t)(b * 512 + qbase + p * 16 + n16) * 128 + h * 32 + quad * 8;
        U8 uh, ul;
#pragma unroll
        for (int j = 0; j < 8; j++) {
            float f = qp[j] * 0.17677669529663687f;
            u16 hi = f2bf(f);
            uh.s[j] = hi;
            ul.s[j] = f2bf(f - bf2f(hi));
        }
        qhi[p] = uh.v; qlo[p] = ul.v;
    }

    const f32x4 zero = {0.f, 0.f, 0.f, 0.f};

    float m[2][4];
#pragma unroll
    for (int p = 0; p < 2; p++)
#pragma unroll
        for (int r = 0; r < 4; r++) m[p][r] = -1e30f;

    for (int j0 = 0; j0 < 512; j0 += 16) {
        U8 ub; ub.q = *(const uint4*)(khi + (size_t)(bh * 512 + j0 + n16) * 32 + quad * 8);
#pragma unroll
        for (int p = 0; p < 2; p++) {
            f32x4 s = mfma16(qhi[p], ub.v, zero);
#pragma unroll
            for (int r = 0; r < 4; r++) m[p][r] = fmaxf(m[p][r], s[r]);
        }
    }
#pragma unroll
    for (int p = 0; p < 2; p++)
#pragma unroll
        for (int r = 0; r < 4; r++) {
            float mv = m[p][r];
#pragma unroll
            for (int mask = 1; mask < 16; mask <<= 1) mv = fmaxf(mv, __shfl_xor(mv, mask));
            m[p][r] = mv;
        }

    float l[2][4] = {{0.f, 0.f, 0.f, 0.f}, {0.f, 0.f, 0.f, 0.f}};
    f32x4 O[2][2];
#pragma unroll
    for (int p = 0; p < 2; p++)
#pragma unroll
        for (int dt = 0; dt < 2; dt++) O[p][dt] = zero;

    u16* tr[2] = { transit[w * 2 + 0], transit[w * 2 + 1] };

    for (int jb = 0; jb < 512; jb += 32) {
#pragma unroll
        for (int jt = 0; jt < 2; jt++) {
            const int j0 = jb + jt * 16;
            const size_t kidx = (size_t)(bh * 512 + j0 + n16) * 32 + quad * 8;
            U8 uh; uh.q = *(const uint4*)(khi + kidx);
            U8 ul; ul.q = *(const uint4*)(klo + kidx);
#pragma unroll
            for (int p = 0; p < 2; p++) {
                f32x4 s = mfma16(qhi[p], uh.v, zero);
                s = mfma16(qhi[p], ul.v, s);
                s = mfma16(qlo[p], uh.v, s);
#pragma unroll
                for (int r = 0; r < 4; r++) {
                    float pr = __expf(s[r] - m[p][r]);
                    u16 pb = f2bf(pr);
                    l[p][r] += bf2f(pb);
                    tr[p][(quad * 4 + r) * 36 + jt * 16 + n16] = pb;
                }
            }
        }
        bf16x8 A[2];
#pragma unroll
        for (int p = 0; p < 2; p++) {
            const u16* trp = tr[p];
            const int off = n16 * 36 + quad * 8;
            uint2 lo = *(const uint2*)(trp + off);
            uint2 hi2 = *(const uint2*)(trp + off + 4);
            U8 ua; ua.q = make_uint4(lo.x, lo.y, hi2.x, hi2.y);
            A[p] = ua.v;
        }
#pragma unroll
        for (int dt = 0; dt < 2; dt++) {
            U8 uv; uv.q = *(const uint4*)(vT + (size_t)(bh * 32 + dt * 16 + n16) * 512 + jb + quad * 8);
#pragma unroll
            for (int p = 0; p < 2; p++) O[p][dt] = mfma16(A[p], uv.v, O[p][dt]);
        }
    }

#pragma unroll
    for (int p = 0; p < 2; p++)
#pragma unroll
        for (int r = 0; r < 4; r++) {
            float lv = l[p][r];
#pragma unroll
            for (int mask = 1; mask < 16; mask <<= 1) lv += __shfl_xor(lv, mask);
            float inv = 1.0f / lv;
#pragma unroll
            for (int dt = 0; dt < 2; dt++)
                ao[(size_t)(b * 512 + qbase + p * 16 + quad * 4 + r) * 128 + h * 32 + dt * 16 + n16]
                    = O[p][dt][r] * inv;
        }
}

// ---------------------------------------------------------------------------
extern "C" void kernel_launch(void* const* d_in, const int* in_sizes, int n_in,
                              void* d_out, int out_size, void* d_ws, size_t ws_size,
                              hipStream_t stream) {
    const float* x    = (const float*)d_in[0];
    const int*   ei   = (const int*)d_in[1];
    const float* ee   = (const float*)d_in[2];
    // d_in[3] = batch (unused; uniform graphs)
    const float* Wg   = (const float*)d_in[4];
    const float* bg   = (const float*)d_in[5];
    const float* root = (const float*)d_in[6];
    const float* Wq   = (const float*)d_in[7];
    const float* Wkv  = (const float*)d_in[8];
    const float* Wo   = (const float*)d_in[9];
    const float* bo   = (const float*)d_in[10];

    // Workspace: 67.4 MB (known-good size)
    char* ws = (char*)d_ws;
    int*   cnt_row = (int*)ws;                       // 128 KB
    float* dinv    = (float*)(ws + 131072);          // 128 KB
    float* buf1    = (float*)(ws + 262144);          // 16 MB: h0 -> q -> attn_out
    float* hbuf    = buf1 + 4194304;                 // 16 MB: h -> khi/klo
    float* kv      = hbuf + 4194304;                 // 32 MB
    u16*   khi     = (u16*)hbuf;                     // 8 MB (after h dead)
    u16*   klo     = khi + 4194304;                  // 8 MB
    u16*   vT      = (u16*)d_out;                    // 8 MB scratch (overwritten by final gemm)
    // CSR scratch sub-allocated at start of kv region (dead until kv-gemm):
    int*   cnt_col = (int*)kv;                       // 128 KB
    int*   offs    = cnt_col + 32768;                // 128 KB + 4B
    int*   cur     = offs + 32769;                   // 128 KB
    int2*  pairs   = (int2*)(cur + 32768 + 1023);    // 4 MB (int2-aligned region)

    hipMemsetAsync(cnt_row, 0, 131072, stream);
    hipMemsetAsync(cnt_col, 0, 131072, stream);

    hist_kernel<<<2048, 256, 0, stream>>>(ei, cnt_row, cnt_col);
    dinv_kernel<<<128, 256, 0, stream>>>(cnt_row, dinv);
    scan_kernel<<<1, 1024, 0, stream>>>(cnt_col, offs, cur);
    scatter_kernel<<<2048, 256, 0, stream>>>(ei, cur, pairs);

    // h0 = x @ W_gcn + b_gcn
    gemm_kernel<128><<<4096, 128, 0, stream>>>(x, Wg, bg, buf1);

    // h = CSR gather + self term  (atomic-free, replaces msg+combine+memset)
    gather_kernel<<<32768, 128, 0, stream>>>(pairs, offs, cnt_row, dinv, buf1, ee, root, hbuf);

    // q = h @ Wq ; kv = h @ Wkv
    gemm_kernel<128><<<4096, 128, 0, stream>>>(hbuf, Wq, nullptr, buf1);
    gemm_kernel<256><<<4096, 256, 0, stream>>>(hbuf, Wkv, nullptr, kv);

    // prep: kv -> khi/klo (over dead h) + vT (in d_out)
    prep_kernel<<<256, 256, 0, stream>>>(kv, khi, klo, vT);

    // MFMA attention -> buf1 (aliases q; per-block disjoint read/write regions)
    attn_mfma_kernel<<<dim3(4, 256), 256, 0, stream>>>(buf1, khi, klo, vT, buf1);

    // out = attn_out @ Wout + b_out
    gemm_kernel<128><<<4096, 128, 0, stream>>>(buf1, Wo, bo, (float*)d_out);
}